// Round 4
// baseline (179.688 us; speedup 1.0000x reference)
//
#include <hip/hip_runtime.h>
#include <stdint.h>

// SelfAttention1D: B=8, C=256, L=2048, D=32, fp32 in/out, bf16 MFMA compute.
//
// ws layout (bytes):
//   Wh  @ 0x000000 : bf16 [320][256]   rows 0-31 Wq, 32-63 Wk, 64-319 Wv (160 KB)
//   Qh  @ 0x040000 : bf16 [B][L][32]   Q pre-scaled by (1/sqrt(D))*log2(e) (1 MB)
//   Kth @ 0x140000 : bf16 [B][L][32]   K^T, d-contiguous (1 MB)
//   Vh  @ 0x240000 : bf16 [B][256][L]  V, j-contiguous (8 MB)
// total 10.25 MB

#define BB 8
#define CC 256
#define LL 2048
#define DD 32

typedef unsigned short u16;
typedef __attribute__((ext_vector_type(8))) short short8;
typedef __attribute__((ext_vector_type(4))) float f32x4;

#define SCALE_LOG2E 0.2550348612f

static __device__ __forceinline__ uint32_t pack2bf16(float hi, float lo) {
    return (__float_as_uint(hi) & 0xFFFF0000u) | (__float_as_uint(lo) >> 16);
}

static __device__ __forceinline__ float fexp2(float v) {
#if __has_builtin(__builtin_amdgcn_exp2f)
    return __builtin_amdgcn_exp2f(v);
#else
    return exp2f(v);
#endif
}

static __device__ __forceinline__ float frcp(float v) {
#if __has_builtin(__builtin_amdgcn_rcpf)
    return __builtin_amdgcn_rcpf(v);
#else
    return 1.0f / v;
#endif
}

// ---------------- kernel 1: W -> bf16 ----------------
__global__ __launch_bounds__(256) void prep_w_kernel(
    const float* __restrict__ Wq, const float* __restrict__ Wk,
    const float* __restrict__ Wv, u16* __restrict__ Wh)
{
    int idx = blockIdx.x * 256 + threadIdx.x;     // 320 rows * 64 float4
    int r = idx >> 6;
    int c4 = (idx & 63) << 2;
    const float* src;
    if (r < 32)       src = Wq + (size_t)r * CC + c4;
    else if (r < 64)  src = Wk + (size_t)(r - 32) * CC + c4;
    else              src = Wv + (size_t)(r - 64) * CC + c4;
    float4 v = *(const float4*)src;
    uint2 o;
    o.x = pack2bf16(v.y, v.x);
    o.y = pack2bf16(v.w, v.z);
    *(uint2*)(Wh + (size_t)r * CC + c4) = o;
}

// ---------------- kernel 2: QKV projection ----------------
// grid 512 = 8 b x 64 l-tiles(32), 512 thr (8 waves), 2 blocks/CU.
__global__ __launch_bounds__(512, 2) void proj_kernel(
    const float* __restrict__ x, const u16* __restrict__ Wh,
    const float* __restrict__ bq, const float* __restrict__ bk,
    const float* __restrict__ bv,
    u16* __restrict__ Qh, u16* __restrict__ Kth, u16* __restrict__ Vh)
{
    __shared__ u16 xls[32 * 264];        // 16.9 KB
    __shared__ __attribute__((aligned(16))) u16 vls[256 * 40]; // 20.5 KB
    const int blk = blockIdx.x;
    const int b = blk & 7;
    const int l0 = (blk >> 3) << 5;
    const int tid = threadIdx.x;
    const int w = tid >> 6;
    const int lane = tid & 63;
    const int ln = lane & 15;
    const int q = lane >> 4;

#pragma unroll
    for (int cc = 0; cc < 4; ++cc) {
        const int c = cc * 64 + (tid >> 3);
        const int l4 = (tid & 7) * 4;
        const float4 v = *(const float4*)(x + ((size_t)(b * CC + c)) * LL + l0 + l4);
        xls[(l4 + 0) * 264 + c] = (u16)(__float_as_uint(v.x) >> 16);
        xls[(l4 + 1) * 264 + c] = (u16)(__float_as_uint(v.y) >> 16);
        xls[(l4 + 2) * 264 + c] = (u16)(__float_as_uint(v.z) >> 16);
        xls[(l4 + 3) * 264 + c] = (u16)(__float_as_uint(v.w) >> 16);
    }
    __syncthreads();

    const int wl = w & 1;
    const int wm = w >> 1;               // 0..3 -> 80 rows each
    const int mbase = wm * 80;
    const int l = l0 + wl * 16 + ln;
    const int li = wl * 16 + ln;

    f32x4 acc[5];
#pragma unroll
    for (int i = 0; i < 5; ++i) acc[i] = (f32x4){0.f, 0.f, 0.f, 0.f};

#pragma unroll
    for (int c0 = 0; c0 < CC; c0 += 32) {
        const short8 bf = *(const short8*)(&xls[(wl * 16 + ln) * 264 + c0 + q * 8]);
#pragma unroll
        for (int mt = 0; mt < 5; ++mt) {
            const short8 af = *(const short8*)(Wh + (size_t)(mbase + mt * 16 + ln) * CC + c0 + q * 8);
            acc[mt] = __builtin_amdgcn_mfma_f32_16x16x32_bf16(af, bf, acc[mt], 0, 0, 0);
        }
    }

#pragma unroll
    for (int mt = 0; mt < 5; ++mt) {
        const int rg = mbase + mt * 16 + q * 4;   // global output row
        if (rg < 32) {                   // Q rows, pre-scaled
            float v0 = (acc[mt][0] + bq[rg + 0]) * SCALE_LOG2E;
            float v1 = (acc[mt][1] + bq[rg + 1]) * SCALE_LOG2E;
            float v2 = (acc[mt][2] + bq[rg + 2]) * SCALE_LOG2E;
            float v3 = (acc[mt][3] + bq[rg + 3]) * SCALE_LOG2E;
            uint2 o; o.x = pack2bf16(v1, v0); o.y = pack2bf16(v3, v2);
            *(uint2*)(Qh + ((size_t)(b * LL) + l) * DD + rg) = o;
        } else if (rg < 64) {            // K rows
            const int rk = rg - 32;
            float v0 = acc[mt][0] + bk[rk + 0];
            float v1 = acc[mt][1] + bk[rk + 1];
            float v2 = acc[mt][2] + bk[rk + 2];
            float v3 = acc[mt][3] + bk[rk + 3];
            uint2 o; o.x = pack2bf16(v1, v0); o.y = pack2bf16(v3, v2);
            *(uint2*)(Kth + ((size_t)(b * LL) + l) * DD + rk) = o;
        } else {                         // V rows -> LDS transpose tile
            const int cv = rg - 64;
#pragma unroll
            for (int rr = 0; rr < 4; ++rr) {
                const float v = acc[mt][rr] + bv[cv + rr];
                vls[(cv + rr) * 40 + li] = (u16)(__float_as_uint(v) >> 16);
            }
        }
    }

    __syncthreads();
    // cooperative coalesced V store: 256 rows x 64 B
    {
        const int row = tid >> 1;
        const int h = (tid & 1) * 16;    // u16 offset within row
        const u16* src = &vls[row * 40 + h];
        const uint4 v0 = *(const uint4*)(src);
        const uint4 v1 = *(const uint4*)(src + 8);
        uint4* dst = (uint4*)(Vh + ((size_t)(b * CC) + row) * LL + l0 + h);
        dst[0] = v0;
        dst[1] = v1;
    }
}

// ---------------- kernel 3: fused attention (c-tile 128 x i-tile 128) ----------------
// grid 256 = (b = blk&7 -> XCD L2 affinity) x (ch = c-half) x (16 i-tiles of 128).
// 1 block/CU. 512 thr (8 waves): wc = w>>2 (64-c slice of this block's 128-c
// half), wj = w&3 (j-slices jb = n*128 + wj*32, n=0..15). Barrier-free main
// loop (R0 schedule: V loads at iter top consumed after S; K prefetch 1 iter
// ahead; wave-private P through LDS). vs R0: i-tile 64->128 and c-tile
// 256->128 per block cuts per-CU L2 line traffic 1.25 MB -> ~0.9 MB (V read
// per block: 128c x 2048j = 512 KB, was 1 MB), which is the measured
// bottleneck (~6 cyc per 64B L2 line/CU across R0-R3). Per-wave acc stays
// 128 regs (64c x 128i / 64 lanes).
__global__ __launch_bounds__(512, 1) void attn_kernel(
    const u16* __restrict__ Qh, const u16* __restrict__ Kth,
    const u16* __restrict__ Vh, const float* __restrict__ x,
    const float* __restrict__ gamma, float* __restrict__ out)
{
    __shared__ __attribute__((aligned(16))) u16 pbuf[8][128 * 40]; // 80 KB
    __shared__ float obuf[128 * 132];    // 67.6 KB
    __shared__ float lbuf[8 * 128];      // 4 KB

    const int blk = blockIdx.x;
    const int b = blk & 7;
    const int ch = (blk >> 3) & 1;       // c-half (128 channels)
    const int i0 = (blk >> 4) << 7;      // i-tile of 128
    const int tid = threadIdx.x;
    const int w = tid >> 6;              // 0..7
    const int wc = w >> 2;               // 0..1 -> 64-c slice within half
    const int wj = w & 3;                // 0..3 -> 32-j slice
    const int lane = tid & 63;
    const int ln = lane & 15;
    const int q = lane >> 4;

    u16* pb = &pbuf[w][0];
    const u16* Qb = Qh + ((size_t)(b * LL) + i0) * DD;
    const u16* Kb = Kth + (size_t)(b * LL) * DD;
    const u16* Vb = Vh + ((size_t)(b * CC) + ch * 128 + wc * 64) * LL;

    short8 qf[8];
#pragma unroll
    for (int it = 0; it < 8; ++it)
        qf[it] = *(const short8*)(Qb + (size_t)(it * 16 + ln) * DD + q * 8);

    const f32x4 zf = {0.f, 0.f, 0.f, 0.f};
    f32x4 oacc[4][8];                    // [ct][it] = 128 regs
#pragma unroll
    for (int a = 0; a < 4; ++a)
#pragma unroll
        for (int c = 0; c < 8; ++c) oacc[a][c] = zf;
    float lsum[8] = {0.f, 0.f, 0.f, 0.f, 0.f, 0.f, 0.f, 0.f};

    // K prefetch for iter 0
    short8 kf0 = *(const short8*)(Kb + (size_t)(wj * 32 + ln) * DD + q * 8);
    short8 kf1 = *(const short8*)(Kb + (size_t)(wj * 32 + 16 + ln) * DD + q * 8);

    for (int n = 0; n < 16; ++n) {
        const int jb = n * 128 + wj * 32;
        const int jnx = (n < 15) ? (n + 1) * 128 + wj * 32 : jb;

        // V loads for THIS iter (consumed after S phase -> latency hidden)
        short8 vf[4];
#pragma unroll
        for (int ct = 0; ct < 4; ++ct)
            vf[ct] = *(const short8*)(Vb + (size_t)(ct * 16 + ln) * LL + jb + q * 8);
        // K prefetch for next iter
        const short8 kn0 = *(const short8*)(Kb + (size_t)(jnx + ln) * DD + q * 8);
        const short8 kn1 = *(const short8*)(Kb + (size_t)(jnx + 16 + ln) * DD + q * 8);

        // ---- S phase: S^T = K.Q^T (32 j x 128 i), exp2, P -> private LDS ----
#pragma unroll
        for (int jt = 0; jt < 2; ++jt) {
            const short8 kf = jt ? kf1 : kf0;
#pragma unroll
            for (int it = 0; it < 8; ++it) {
                const f32x4 st = __builtin_amdgcn_mfma_f32_16x16x32_bf16(kf, qf[it], zf, 0, 0, 0);
                const float e0 = fexp2(st[0]), e1 = fexp2(st[1]);
                const float e2 = fexp2(st[2]), e3 = fexp2(st[3]);
                lsum[it] += (e0 + e1) + (e2 + e3);
                uint2 d; d.x = pack2bf16(e1, e0); d.y = pack2bf16(e3, e2);
                *(uint2*)(&pb[(it * 16 + ln) * 40 + jt * 16 + q * 4]) = d;
            }
        }

        // ---- read back as B-frags (same wave; compiler emits lgkmcnt wait) ----
        // ---- PV: O^T += V.P^T over exclusive 64-c slice, split in it-halves
        //      to cap pf liveness at 16 regs ----
#pragma unroll
        for (int ih = 0; ih < 2; ++ih) {
            short8 pf[4];
#pragma unroll
            for (int it = 0; it < 4; ++it)
                pf[it] = *(const short8*)(&pb[((ih * 4 + it) * 16 + ln) * 40 + q * 8]);
#pragma unroll
            for (int ct = 0; ct < 4; ++ct)
#pragma unroll
                for (int it = 0; it < 4; ++it)
                    oacc[ct][ih * 4 + it] = __builtin_amdgcn_mfma_f32_16x16x32_bf16(
                        vf[ct], pf[it], oacc[ct][ih * 4 + it], 0, 0, 0);
        }

        kf0 = kn0; kf1 = kn1;
    }

    // ---- l: reduce over q within wave; publish per-wave partials ----
#pragma unroll
    for (int it = 0; it < 8; ++it) {
        float s = lsum[it];
        s += __shfl_xor(s, 16);
        s += __shfl_xor(s, 32);
        lsum[it] = s;
    }
    if (q == 0) {
#pragma unroll
        for (int it = 0; it < 8; ++it) lbuf[w * 128 + it * 16 + ln] = lsum[it];
    }

    // ---- O reduction over wj (4 serialized passes, disjoint c across wc) ----
#pragma unroll
    for (int p = 0; p < 4; ++p) {
        if (wj == p) {
#pragma unroll
            for (int ct = 0; ct < 4; ++ct)
#pragma unroll
                for (int it = 0; it < 8; ++it) {
                    const int i = it * 16 + ln;
#pragma unroll
                    for (int r = 0; r < 4; ++r) {
                        const int c = wc * 64 + ct * 16 + q * 4 + r;
                        if (p == 0) obuf[c * 132 + i] = oacc[ct][it][r];
                        else        obuf[c * 132 + i] += oacc[ct][it][r];
                    }
                }
        }
        __syncthreads();
    }

    // ---- finalize: out = gamma * O/l + x (coalesced float4) ----
    // lbuf summed over all 8 waves double-counts l (2 wc duplicates) -> 2/s.
    const float g = gamma[0];
    const int i4 = (tid & 31) * 4;       // 0..124
    const int crow = tid >> 5;           // 0..15
    float4 sv = {0.f, 0.f, 0.f, 0.f};
#pragma unroll
    for (int ww = 0; ww < 8; ++ww) {
        const float4 lv = *(const float4*)&lbuf[ww * 128 + i4];
        sv.x += lv.x; sv.y += lv.y; sv.z += lv.z; sv.w += lv.w;
    }
    float4 li;
    li.x = 2.0f * frcp(sv.x); li.y = 2.0f * frcp(sv.y);
    li.z = 2.0f * frcp(sv.z); li.w = 2.0f * frcp(sv.w);

#pragma unroll
    for (int cc = 0; cc < 8; ++cc) {
        const int c = cc * 16 + crow;    // 0..127 within half
        const float4 ov = *(const float4*)&obuf[c * 132 + i4];
        const size_t idx = ((size_t)(b * CC + ch * 128 + c)) * LL + i0 + i4;
        const float4 xv = *(const float4*)(x + idx);
        float4 o;
        o.x = g * (ov.x * li.x) + xv.x;
        o.y = g * (ov.y * li.y) + xv.y;
        o.z = g * (ov.z * li.z) + xv.z;
        o.w = g * (ov.w * li.w) + xv.w;
        *(float4*)(out + idx) = o;
    }
}

// ---------------- launcher ----------------
extern "C" void kernel_launch(void* const* d_in, const int* in_sizes, int n_in,
                              void* d_out, int out_size, void* d_ws, size_t ws_size,
                              hipStream_t stream)
{
    const float* x     = (const float*)d_in[0];
    const float* Wq    = (const float*)d_in[1];
    const float* bq    = (const float*)d_in[2];
    const float* Wk    = (const float*)d_in[3];
    const float* bk    = (const float*)d_in[4];
    const float* Wv    = (const float*)d_in[5];
    const float* bv    = (const float*)d_in[6];
    const float* gamma = (const float*)d_in[7];
    float* out = (float*)d_out;

    uint8_t* ws = (uint8_t*)d_ws;
    u16* Wh  = (u16*)(ws + 0x000000);
    u16* Qh  = (u16*)(ws + 0x040000);
    u16* Kth = (u16*)(ws + 0x140000);
    u16* Vh  = (u16*)(ws + 0x240000);

    prep_w_kernel<<<80, 256, 0, stream>>>(Wq, Wk, Wv, Wh);
    proj_kernel<<<512, 512, 0, stream>>>(x, Wh, bq, bk, bv, Qh, Kth, Vh);
    attn_kernel<<<256, 512, 0, stream>>>(Qh, Kth, Vh, x, gamma, out);
}